// Round 9
// baseline (232.795 us; speedup 1.0000x reference)
//
#include <hip/hip_runtime.h>

typedef unsigned short u16;
typedef unsigned int u32;
typedef short short8 __attribute__((ext_vector_type(8)));
typedef float f32x4 __attribute__((ext_vector_type(4)));
typedef float f32x16 __attribute__((ext_vector_type(16)));

#define NTOK 2009
#define M8   8036      // 4*2009
#define DMOD 1024
// packed fragment buffers: [bh][tile(63)][...][256] u16; 2048 u16 per tile
#define PKBH 129024    // 63*2048 u16 per bh

static __device__ __forceinline__ u16 f2bf(float f) {
  unsigned int x = __float_as_uint(f);
  x += 0x7fffu + ((x >> 16) & 1u);
  return (u16)(x >> 16);
}
static __device__ __forceinline__ float bf2f(u16 u) {
  return __uint_as_float((unsigned int)u << 16);
}
static __device__ __forceinline__ u32 pk2(float a, float b) {
  return (u32)f2bf(a) | ((u32)f2bf(b) << 16);
}
static __device__ __forceinline__ u32 cvtpk(float a, float b) {
  u32 d;
  asm("v_cvt_pk_bf16_f32 %0, %1, %2" : "=v"(d) : "v"(a), "v"(b));
  return d;
}
static __device__ __forceinline__ void gload_lds16(const void* g, void* l) {
  __builtin_amdgcn_global_load_lds(
      (const __attribute__((address_space(1))) void*)g,
      (__attribute__((address_space(3))) void*)l, 16, 0, 0);
}

// ---------------- converts ----------------
__global__ void k_conv_x(const float* __restrict__ x, u16* __restrict__ xb) {
  int i = blockIdx.x * 256 + threadIdx.x;
  float4 v = ((const float4*)x)[i];
  unsigned int a = (unsigned int)f2bf(v.x) | ((unsigned int)f2bf(v.y) << 16);
  unsigned int b = (unsigned int)f2bf(v.z) | ((unsigned int)f2bf(v.w) << 16);
  ((uint2*)xb)[i] = make_uint2(a, b);
}

__global__ void k_conv_wcat(const float* __restrict__ Wqkv, const float* __restrict__ Wqs,
                            u16* __restrict__ WtCat) {
  int i = blockIdx.x * 256 + threadIdx.x;
  int n = i >> 10, k = i & 1023;
  float v = (n < 768) ? Wqkv[k * 768 + n] : Wqs[k * 512 + (n - 768)];
  WtCat[i] = f2bf(v);
}

__global__ void k_conv_wout(const float* __restrict__ Wout, u16* __restrict__ WtOut) {
  int i = blockIdx.x * 256 + threadIdx.x;
  int n = i >> 8, k = i & 255;
  WtOut[i] = f2bf(Wout[k * 1024 + n]);
}

// ---------------- projection GEMM (m97-style): [8036,1024] x [1280,1024]^T ----
__global__ __launch_bounds__(256) void k_gemm_proj(
    const u16* __restrict__ A, const u16* __restrict__ Bt,
    u16* __restrict__ Qp, u16* __restrict__ Kp, u16* __restrict__ Vp,
    u16* __restrict__ Qsb, u16* __restrict__ Ksb)
{
  __shared__ u16 Asm[128 * 64];
  __shared__ u16 Bsm[128 * 64];
  int mt = blockIdx.x * 128, nt = blockIdx.y * 128;
  int tid = threadIdx.x, lane = tid & 63, w = tid >> 6;
  int wm = w >> 1, wn = w & 1;
  int fr = lane & 15, fq = lane >> 4;
  int srow = w * 32 + (lane >> 3);
  int scol = (lane & 7) * 8;
  f32x4 acc[4][4];
#pragma unroll
  for (int a = 0; a < 4; ++a)
#pragma unroll
    for (int b = 0; b < 4; ++b) acc[a][b] = (f32x4){0.f, 0.f, 0.f, 0.f};

  for (int kt = 0; kt < 1024; kt += 64) {
#pragma unroll
    for (int j = 0; j < 4; ++j) {
      int r = srow + j * 8;
      int am = mt + r; if (am >= M8) am = 0;
      gload_lds16(A + (size_t)am * 1024 + kt + scol, Asm + (size_t)(w * 32 + j * 8) * 64);
      gload_lds16(Bt + (size_t)(nt + r) * 1024 + kt + scol, Bsm + (size_t)(w * 32 + j * 8) * 64);
    }
    __syncthreads();
#pragma unroll
    for (int cs = 0; cs < 2; ++cs) {
      short8 af[4], bf[4];
#pragma unroll
      for (int i = 0; i < 4; ++i) {
        af[i] = *(const short8*)&Asm[(size_t)(wm * 64 + i * 16 + fr) * 64 + cs * 32 + fq * 8];
        bf[i] = *(const short8*)&Bsm[(size_t)(wn * 64 + i * 16 + fr) * 64 + cs * 32 + fq * 8];
      }
#pragma unroll
      for (int mi = 0; mi < 4; ++mi)
#pragma unroll
        for (int ni = 0; ni < 4; ++ni)
          acc[mi][ni] = __builtin_amdgcn_mfma_f32_16x16x32_bf16(af[mi], bf[ni], acc[mi][ni], 0, 0, 0);
    }
    __syncthreads();
  }

#pragma unroll
  for (int ni = 0; ni < 4; ++ni) {
    int n = nt + wn * 64 + ni * 16 + fr;
    int g = n >> 6, d = n & 63;
    int h = g & 3, sel = g >> 2;   // 0=q 1=k 2=v 3=qs 4=ks
    float scl = (sel == 0 || sel == 3) ? 0.0625f : 1.0f;
#pragma unroll
    for (int mi = 0; mi < 4; ++mi) {
#pragma unroll
      for (int i = 0; i < 4; ++i) {
        int m = mt + wm * 64 + mi * 16 + fq * 4 + i;
        if (m >= M8) continue;
        int b_ = m / NTOK, tok = m - b_ * NTOK;
        int bh = b_ * 4 + h;
        u16 val = f2bf(acc[mi][ni][i] * scl);
        if (sel <= 1) {
          u16* dst = sel == 0 ? Qp : Kp;
          size_t idx = ((((size_t)bh * 63 + (tok >> 5)) * 4 + (d >> 4)) * 2 + ((d >> 3) & 1)) * 256
                       + (tok & 31) * 8 + (d & 7);
          dst[idx] = val;
        } else if (sel == 2) {
          size_t idx = (((((size_t)bh * 63 + (tok >> 5)) * 2 + (d >> 5)) * 2 + ((tok >> 4) & 1)) * 2
                        + ((tok >> 3) & 1)) * 256 + (d & 31) * 8 + (tok & 7);
          Vp[idx] = val;
        } else {
          u16* p = (sel == 3) ? Qsb : Ksb;
          p[((size_t)bh * NTOK + tok) * 64 + d] = val;
        }
      }
    }
  }
}

// ---------------- block-diagonal self dots (Qs pre-scaled) ----------------
__global__ void k_self(const u16* __restrict__ Qs, const u16* __restrict__ Ks,
                       float* __restrict__ selfS) {
  int blk = blockIdx.x;            // bh*200 + agent
  int bh = blk / 200, a = blk % 200;
  int t = threadIdx.x;
  if (t >= 100) return;
  int ri = t / 10, rj = t % 10;
  const u16* qp = &Qs[((size_t)bh * NTOK + a * 10 + ri) * 64];
  const u16* kp = &Ks[((size_t)bh * NTOK + a * 10 + rj) * 64];
  float s = 0.f;
#pragma unroll 8
  for (int k = 0; k < 64; ++k) s += bf2f(qp[k]) * bf2f(kp[k]);
  selfS[(size_t)blk * 100 + t] = s;
}

// ---------------- fused attention v9: aligned dword attn stores ------------
// Same as v8 (compute loop + store loop) but the attn write-out uses
// dword-per-lane stores (always 4B-aligned; rows are only 4B-aligned since
// 2009%4==1, so float4 stores were split 2x at the TA). P-staging LDS
// aliases s_o (disjoint per-wave lifetimes).
__global__ __launch_bounds__(256, 2) void k_attn9(
    const u16* __restrict__ Qp, const u16* __restrict__ Kp,
    const u16* __restrict__ Vp, const float* __restrict__ selfS,
    float* __restrict__ attn, u16* __restrict__ Ob)
{
  __shared__ float s_sum[4][32];
  __shared__ float s_o[4][64][32];   // 32 KB; first 4 KB of each wave's slice
                                     // doubles as the P transpose buffer
  int bh = blockIdx.x;
  int qt = blockIdx.y;
  int q0 = qt * 32;
  int tid = threadIdx.x;
  int lane = tid & 63, w = tid >> 6;
  int ql = lane & 31, h = lane >> 5;
  int qg = q0 + ql;
  int lo8 = ql * 8;

  const u16* qbase = Qp + (size_t)bh * PKBH + (size_t)qt * 2048;
  const u16* kbase = Kp + (size_t)bh * PKBH;
  const u16* vbase = Vp + (size_t)bh * PKBH;

  short8 qf[4];
#pragma unroll
  for (int c = 0; c < 4; ++c)
    qf[c] = *(const short8*)&qbase[(c * 2 + h) * 256 + lo8];

  // block-diagonal patch band
  int qa = (qg < 2000) ? (qg / 10) : -1;
  int band_lo = 1 << 30, band_hi = -(1 << 30);
  if (q0 < 2000) {
    int hi_row = (q0 + 31 < 1999) ? q0 + 31 : 1999;
    band_lo = (q0 / 10) * 10;
    band_hi = (hi_row / 10) * 10 + 10;
  }
  const float* sfb = &selfS[(size_t)bh * 20000];

  int t0 = w * 16;
  int t1 = t0 + 16; if (t1 > 63) t1 = 63;

  u32 pb[16][8];                 // packed unnormalized e (bf16 pairs)
  short8 kf[4], kfn[4], vf[4];
  f32x16 oacc0 = {}, oacc1 = {};

  // ====== loop 1: loads + QK + exp + pack + PV (no global stores) ========
#pragma unroll
  for (int c = 0; c < 4; ++c)
    kf[c] = *(const short8*)&kbase[(size_t)t0 * 2048 + (c * 2 + h) * 256 + lo8];
  float ssum = 0.f;
#pragma unroll
  for (int i = 0; i < 16; ++i) {
    int t = t0 + i;
    if (t < t1) {
      int tn = (t + 1 < t1) ? t + 1 : t0;
#pragma unroll
      for (int c = 0; c < 4; ++c)
        vf[c] = *(const short8*)&vbase[(size_t)t * 2048 + (c * 2 + h) * 256 + lo8];
#pragma unroll
      for (int c = 0; c < 4; ++c)
        kfn[c] = *(const short8*)&kbase[(size_t)tn * 2048 + (c * 2 + h) * 256 + lo8];
      f32x16 acc = {};
#pragma unroll
      for (int c = 0; c < 4; ++c)
        acc = __builtin_amdgcn_mfma_f32_32x32x16_bf16(kf[c], qf[c], acc, 0, 0, 0);
      int kt = t * 32;
      float e[16];
      if ((kt < band_hi) && (kt + 32 > band_lo)) {
#pragma unroll
        for (int r = 0; r < 16; ++r) {
          int kc = kt + (r & 3) + 8 * (r >> 2) + 4 * h;
          float sc = acc[r];
          if (qa >= 0 && kc < 2000 && (kc / 10) == qa)
            sc = sfb[qa * 100 + (qg - qa * 10) * 10 + (kc - qa * 10)];
          e[r] = __expf(sc);
        }
      } else {
#pragma unroll
        for (int r = 0; r < 16; ++r) e[r] = __expf(acc[r]);
      }
      if (t == 62) {             // mask k-pad [2009,2016)
#pragma unroll
        for (int r = 0; r < 16; ++r) {
          int kc = kt + (r & 3) + 8 * (r >> 2) + 4 * h;
          if (kc >= NTOK) e[r] = 0.f;
        }
      }
#pragma unroll
      for (int r2 = 0; r2 < 8; ++r2) {
        pb[i][r2] = cvtpk(e[2 * r2], e[2 * r2 + 1]);
        ssum += e[2 * r2] + e[2 * r2 + 1];
      }
      // ---- redistribute pb -> PV B-fragments; PV accumulate ----
      u32 p00 = __shfl_xor(pb[i][0], 32), p01 = __shfl_xor(pb[i][1], 32);
      u32 p10 = __shfl_xor(pb[i][2], 32), p11 = __shfl_xor(pb[i][3], 32);
      u32 p20 = __shfl_xor(pb[i][4], 32), p21 = __shfl_xor(pb[i][5], 32);
      u32 p30 = __shfl_xor(pb[i][6], 32), p31 = __shfl_xor(pb[i][7], 32);
      u32 b0[4], b1[4];
      b0[0] = h ? p10 : pb[i][0];  b0[1] = h ? p11 : pb[i][1];
      b0[2] = h ? pb[i][2] : p00;  b0[3] = h ? pb[i][3] : p01;
      b1[0] = h ? p30 : pb[i][4];  b1[1] = h ? p31 : pb[i][5];
      b1[2] = h ? pb[i][6] : p20;  b1[3] = h ? pb[i][7] : p21;
      short8 B0, B1;
      __builtin_memcpy(&B0, b0, 16);
      __builtin_memcpy(&B1, b1, 16);
      oacc0 = __builtin_amdgcn_mfma_f32_32x32x16_bf16(vf[0], B0, oacc0, 0, 0, 0);
      oacc1 = __builtin_amdgcn_mfma_f32_32x32x16_bf16(vf[2], B0, oacc1, 0, 0, 0);
      oacc0 = __builtin_amdgcn_mfma_f32_32x32x16_bf16(vf[1], B1, oacc0, 0, 0, 0);
      oacc1 = __builtin_amdgcn_mfma_f32_32x32x16_bf16(vf[3], B1, oacc1, 0, 0, 0);
#pragma unroll
      for (int c = 0; c < 4; ++c) kf[c] = kfn[c];
    }
  }
  ssum += __shfl_xor(ssum, 32);
  if (lane < 32) s_sum[w][ql] = ssum;
  __syncthreads();
  float inv = 1.0f / (s_sum[0][ql] + s_sum[1][ql] + s_sum[2][ql] + s_sum[3][ql]);

  // ====== loop 2: pure store stream (aligned dword stores) ===============
  char* pl = (char*)&s_o[w][0][0];   // 4 KB P transpose buffer (aliases s_o[w])
#pragma unroll
  for (int i = 0; i < 16; ++i) {
    int t = t0 + i;
    if (t < t1) {
      int kt = t * 32;
      // ---- unpack + normalize -> swizzled LDS [32 q][32 k] ----
#pragma unroll
      for (int rq = 0; rq < 4; ++rq) {
        u32 ua = pb[i][2 * rq], ub = pb[i][2 * rq + 1];
        f32x4 v = {__uint_as_float(ua << 16) * inv,
                   __uint_as_float(ua & 0xffff0000u) * inv,
                   __uint_as_float(ub << 16) * inv,
                   __uint_as_float(ub & 0xffff0000u) * inv};
        *(f32x4*)(pl + ql * 128 + ((rq * 32 + h * 16) ^ ((ql & 7) << 4))) = v;
      }
      // ---- coalesced dword write-out: 16 insts, 2 x 128B rows each ----
#pragma unroll
      for (int j = 0; j < 16; ++j) {
        int r = j * 2 + (lane >> 5);     // 0..31
        int c = lane & 31;
        float v = *(float*)(pl + r * 128 + ((c * 4) ^ ((r & 7) << 4)));
        int grow = q0 + r;
        int col = kt + c;
        if (grow < NTOK && col < NTOK)
          attn[((size_t)bh * NTOK + grow) * NTOK + col] = v;
      }
    }
  }
  __syncthreads();   // all waves done with the P buffer before s_o reuse

  // ---- combine partial O across waves via LDS (normalize here) ----
#pragma unroll
  for (int r = 0; r < 16; ++r) {
    int d = (r & 3) + 8 * (r >> 2) + 4 * h;
    s_o[w][d][ql] = oacc0[r];
    s_o[w][d + 32][ql] = oacc1[r];
  }
  __syncthreads();
  {
    int q = tid & 31, dg = tid >> 5;          // 8 d's per thread
    int qg2 = q0 + q;
    if (qg2 < NTOK) {
      float invq = 1.0f / (s_sum[0][q] + s_sum[1][q] + s_sum[2][q] + s_sum[3][q]);
      int b_ = bh >> 2, hd = bh & 3;
      u16* orow = &Ob[((size_t)(b_ * NTOK + qg2)) * 256 + hd * 64 + dg * 8];
      u32 wpk[4];
#pragma unroll
      for (int j = 0; j < 4; ++j) {
        int d = dg * 8 + 2 * j;
        float a = (s_o[0][d][q] + s_o[1][d][q] + s_o[2][d][q] + s_o[3][d][q]) * invq;
        float b = (s_o[0][d + 1][q] + s_o[1][d + 1][q] + s_o[2][d + 1][q] + s_o[3][d + 1][q]) * invq;
        wpk[j] = pk2(a, b);
      }
      *(uint4*)orow = make_uint4(wpk[0], wpk[1], wpk[2], wpk[3]);
    }
  }
}

// ---------------- output GEMM (m97-style): [8036,256] x [1024,256]^T + bias --
__global__ __launch_bounds__(256) void k_gemm_out(
    const u16* __restrict__ A, const u16* __restrict__ Bt,
    const float* __restrict__ bias, float* __restrict__ C)
{
  __shared__ u16 Asm[128 * 64];
  __shared__ u16 Bsm[128 * 64];
  int mt = blockIdx.x * 128, nt = blockIdx.y * 128;
  int tid = threadIdx.x, lane = tid & 63, w = tid >> 6;
  int wm = w >> 1, wn = w & 1;
  int fr = lane & 15, fq = lane >> 4;
  int srow = w * 32 + (lane >> 3);
  int scol = (lane & 7) * 8;
  f32x4 acc[4][4];
#pragma unroll
  for (int a = 0; a < 4; ++a)
#pragma unroll
    for (int b = 0; b < 4; ++b) acc[a][b] = (f32x4){0.f, 0.f, 0.f, 0.f};

  for (int kt = 0; kt < 256; kt += 64) {
#pragma unroll
    for (int j = 0; j < 4; ++j) {
      int r = srow + j * 8;
      int am = mt + r; if (am >= M8) am = 0;
      gload_lds16(A + (size_t)am * 256 + kt + scol, Asm + (size_t)(w * 32 + j * 8) * 64);
      gload_lds16(Bt + (size_t)(nt + r) * 256 + kt + scol, Bsm + (size_t)(w * 32 + j * 8) * 64);
    }
    __syncthreads();
#pragma unroll
    for (int cs = 0; cs < 2; ++cs) {
      short8 af[4], bf[4];
#pragma unroll
      for (int i = 0; i < 4; ++i) {
        af[i] = *(const short8*)&Asm[(size_t)(wm * 64 + i * 16 + fr) * 64 + cs * 32 + fq * 8];
        bf[i] = *(const short8*)&Bsm[(size_t)(wn * 64 + i * 16 + fr) * 64 + cs * 32 + fq * 8];
      }
#pragma unroll
      for (int mi = 0; mi < 4; ++mi)
#pragma unroll
        for (int ni = 0; ni < 4; ++ni)
          acc[mi][ni] = __builtin_amdgcn_mfma_f32_16x16x32_bf16(af[mi], bf[ni], acc[mi][ni], 0, 0, 0);
    }
    __syncthreads();
  }

#pragma unroll
  for (int ni = 0; ni < 4; ++ni) {
    int n = nt + wn * 64 + ni * 16 + fr;
    float bn = bias[n];
#pragma unroll
    for (int mi = 0; mi < 4; ++mi)
#pragma unroll
      for (int i = 0; i < 4; ++i) {
        int m = mt + wm * 64 + mi * 16 + fq * 4 + i;
        if (m < M8) C[(size_t)m * DMOD + n] = acc[mi][ni][i] + bn;
      }
  }
}

extern "C" void kernel_launch(void* const* d_in, const int* in_sizes, int n_in,
                              void* d_out, int out_size, void* d_ws, size_t ws_size,
                              hipStream_t stream) {
  (void)in_sizes; (void)n_in; (void)out_size; (void)ws_size;
  const float* x    = (const float*)d_in[0];
  const float* Wqkv = (const float*)d_in[1];
  const float* Wqs  = (const float*)d_in[2];
  const float* Wout = (const float*)d_in[3];
  const float* bout = (const float*)d_in[4];
  float* out  = (float*)d_out;
  float* attn = out + (size_t)M8 * DMOD;

  char* ws = (char*)d_ws;
  u16*   xb    = (u16*)(ws);                      // 16,457,728
  u16*   WtCat = (u16*)(ws + 16457728);           //  2,621,440
  u16*   WtOut = (u16*)(ws + 19079168);           //    524,288
  u16*   Qp    = (u16*)(ws + 19603456);           //  4,128,768
  u16*   Kp    = (u16*)(ws + 23732224);           //  4,128,768
  u16*   Vp    = (u16*)(ws + 27860992);           //  4,128,768
  u16*   Qsb   = (u16*)(ws + 31989760);           //  4,114,432
  u16*   Ksb   = (u16*)(ws + 36104192);           //  4,114,432
  u16*   Ob    = (u16*)(ws + 40218624);           //  4,114,432
  float* selfS = (float*)(ws + 44333056);         //  1,280,000 (end ~45.6 MB)

  k_conv_x<<<dim3(8036), dim3(256), 0, stream>>>(x, xb);
  k_conv_wcat<<<dim3(5120), dim3(256), 0, stream>>>(Wqkv, Wqs, WtCat);
  k_conv_wout<<<dim3(1024), dim3(256), 0, stream>>>(Wout, WtOut);
  k_gemm_proj<<<dim3(63, 10), dim3(256), 0, stream>>>(xb, WtCat, Qp, Kp, Vp, Qsb, Ksb);
  k_self<<<dim3(3200), dim3(128), 0, stream>>>(Qsb, Ksb, selfS);
  k_attn9<<<dim3(16, 63), dim3(256), 0, stream>>>(Qp, Kp, Vp, selfS, attn, Ob);
  k_gemm_out<<<dim3(63, 8), dim3(256), 0, stream>>>(Ob, WtOut, bout, out);
}

// Round 10
// 216.009 us; speedup vs baseline: 1.0777x; 1.0777x over previous
//
#include <hip/hip_runtime.h>

typedef unsigned short u16;
typedef unsigned int u32;
typedef short short8 __attribute__((ext_vector_type(8)));
typedef float f32x4 __attribute__((ext_vector_type(4)));
typedef float f32x16 __attribute__((ext_vector_type(16)));

#define NTOK 2009
#define M8   8036      // 4*2009
#define DMOD 1024
// packed fragment buffers: [bh][tile(63)][...][256] u16; 2048 u16 per tile
#define PKBH 129024    // 63*2048 u16 per bh

static __device__ __forceinline__ u16 f2bf(float f) {
  unsigned int x = __float_as_uint(f);
  x += 0x7fffu + ((x >> 16) & 1u);
  return (u16)(x >> 16);
}
static __device__ __forceinline__ float bf2f(u16 u) {
  return __uint_as_float((unsigned int)u << 16);
}
static __device__ __forceinline__ u32 pk2(float a, float b) {
  return (u32)f2bf(a) | ((u32)f2bf(b) << 16);
}
static __device__ __forceinline__ u32 cvtpk(float a, float b) {
  u32 d;
  asm("v_cvt_pk_bf16_f32 %0, %1, %2" : "=v"(d) : "v"(a), "v"(b));
  return d;
}
static __device__ __forceinline__ void gload_lds16(const void* g, void* l) {
  __builtin_amdgcn_global_load_lds(
      (const __attribute__((address_space(1))) void*)g,
      (__attribute__((address_space(3))) void*)l, 16, 0, 0);
}

// ---------------- converts ----------------
__global__ void k_conv_x(const float* __restrict__ x, u16* __restrict__ xb) {
  int i = blockIdx.x * 256 + threadIdx.x;
  float4 v = ((const float4*)x)[i];
  unsigned int a = (unsigned int)f2bf(v.x) | ((unsigned int)f2bf(v.y) << 16);
  unsigned int b = (unsigned int)f2bf(v.z) | ((unsigned int)f2bf(v.w) << 16);
  ((uint2*)xb)[i] = make_uint2(a, b);
}

__global__ void k_conv_wcat(const float* __restrict__ Wqkv, const float* __restrict__ Wqs,
                            u16* __restrict__ WtCat) {
  int i = blockIdx.x * 256 + threadIdx.x;
  int n = i >> 10, k = i & 1023;
  float v = (n < 768) ? Wqkv[k * 768 + n] : Wqs[k * 512 + (n - 768)];
  WtCat[i] = f2bf(v);
}

__global__ void k_conv_wout(const float* __restrict__ Wout, u16* __restrict__ WtOut) {
  int i = blockIdx.x * 256 + threadIdx.x;
  int n = i >> 8, k = i & 255;
  WtOut[i] = f2bf(Wout[k * 1024 + n]);
}

// ---------------- projection GEMM (m97-style): [8036,1024] x [1280,1024]^T ----
__global__ __launch_bounds__(256) void k_gemm_proj(
    const u16* __restrict__ A, const u16* __restrict__ Bt,
    u16* __restrict__ Qp, u16* __restrict__ Kp, u16* __restrict__ Vp,
    u16* __restrict__ Qsb, u16* __restrict__ Ksb)
{
  __shared__ u16 Asm[128 * 64];
  __shared__ u16 Bsm[128 * 64];
  int mt = blockIdx.x * 128, nt = blockIdx.y * 128;
  int tid = threadIdx.x, lane = tid & 63, w = tid >> 6;
  int wm = w >> 1, wn = w & 1;
  int fr = lane & 15, fq = lane >> 4;
  int srow = w * 32 + (lane >> 3);
  int scol = (lane & 7) * 8;
  f32x4 acc[4][4];
#pragma unroll
  for (int a = 0; a < 4; ++a)
#pragma unroll
    for (int b = 0; b < 4; ++b) acc[a][b] = (f32x4){0.f, 0.f, 0.f, 0.f};

  for (int kt = 0; kt < 1024; kt += 64) {
#pragma unroll
    for (int j = 0; j < 4; ++j) {
      int r = srow + j * 8;
      int am = mt + r; if (am >= M8) am = 0;
      gload_lds16(A + (size_t)am * 1024 + kt + scol, Asm + (size_t)(w * 32 + j * 8) * 64);
      gload_lds16(Bt + (size_t)(nt + r) * 1024 + kt + scol, Bsm + (size_t)(w * 32 + j * 8) * 64);
    }
    __syncthreads();
#pragma unroll
    for (int cs = 0; cs < 2; ++cs) {
      short8 af[4], bf[4];
#pragma unroll
      for (int i = 0; i < 4; ++i) {
        af[i] = *(const short8*)&Asm[(size_t)(wm * 64 + i * 16 + fr) * 64 + cs * 32 + fq * 8];
        bf[i] = *(const short8*)&Bsm[(size_t)(wn * 64 + i * 16 + fr) * 64 + cs * 32 + fq * 8];
      }
#pragma unroll
      for (int mi = 0; mi < 4; ++mi)
#pragma unroll
        for (int ni = 0; ni < 4; ++ni)
          acc[mi][ni] = __builtin_amdgcn_mfma_f32_16x16x32_bf16(af[mi], bf[ni], acc[mi][ni], 0, 0, 0);
    }
    __syncthreads();
  }

#pragma unroll
  for (int ni = 0; ni < 4; ++ni) {
    int n = nt + wn * 64 + ni * 16 + fr;
    int g = n >> 6, d = n & 63;
    int h = g & 3, sel = g >> 2;   // 0=q 1=k 2=v 3=qs 4=ks
    float scl = (sel == 0 || sel == 3) ? 0.0625f : 1.0f;
#pragma unroll
    for (int mi = 0; mi < 4; ++mi) {
#pragma unroll
      for (int i = 0; i < 4; ++i) {
        int m = mt + wm * 64 + mi * 16 + fq * 4 + i;
        if (m >= M8) continue;
        int b_ = m / NTOK, tok = m - b_ * NTOK;
        int bh = b_ * 4 + h;
        u16 val = f2bf(acc[mi][ni][i] * scl);
        if (sel <= 1) {
          u16* dst = sel == 0 ? Qp : Kp;
          size_t idx = ((((size_t)bh * 63 + (tok >> 5)) * 4 + (d >> 4)) * 2 + ((d >> 3) & 1)) * 256
                       + (tok & 31) * 8 + (d & 7);
          dst[idx] = val;
        } else if (sel == 2) {
          size_t idx = (((((size_t)bh * 63 + (tok >> 5)) * 2 + (d >> 5)) * 2 + ((tok >> 4) & 1)) * 2
                        + ((tok >> 3) & 1)) * 256 + (d & 31) * 8 + (tok & 7);
          Vp[idx] = val;
        } else {
          u16* p = (sel == 3) ? Qsb : Ksb;
          p[((size_t)bh * NTOK + tok) * 64 + d] = val;
        }
      }
    }
  }
}

// ---------------- block-diagonal self dots (Qs pre-scaled) ----------------
__global__ void k_self(const u16* __restrict__ Qs, const u16* __restrict__ Ks,
                       float* __restrict__ selfS) {
  int blk = blockIdx.x;            // bh*200 + agent
  int bh = blk / 200, a = blk % 200;
  int t = threadIdx.x;
  if (t >= 100) return;
  int ri = t / 10, rj = t % 10;
  const u16* qp = &Qs[((size_t)bh * NTOK + a * 10 + ri) * 64];
  const u16* kp = &Ks[((size_t)bh * NTOK + a * 10 + rj) * 64];
  float s = 0.f;
#pragma unroll 8
  for (int k = 0; k < 64; ++k) s += bf2f(qp[k]) * bf2f(kp[k]);
  selfS[(size_t)blk * 100 + t] = s;
}

// ---------------- fused attention v10: row-major sequential attn stores ----
// loop1 identical to v8 (loads + QK + exp + pack + PV, no stores).
// loop2: per wave, 4 chunks of 4 tiles: stage packed pb into wave-private
// 8 KB LDS slab (XOR swizzle c^(row&31), conflict-free both sides), then
// write rows as 512B sequential dword runs (chunks ascending -> each wave
// emits a monotone 2 KB stream per row; 4 waves cover the 8 KB row in 4
// parallel sequential streams). DRAM-page-friendly vs prior tile-major 128B
// scatter at 8 KB stride.
__global__ __launch_bounds__(256, 2) void k_attn10(
    const u16* __restrict__ Qp, const u16* __restrict__ Kp,
    const u16* __restrict__ Vp, const float* __restrict__ selfS,
    float* __restrict__ attn, u16* __restrict__ Ob)
{
  __shared__ float s_sum[4][32];
  __shared__ float s_inv[32];
  __shared__ float s_o[4][64][32];   // 32 KB; per-wave 8 KB slice doubles as
                                     // the packed-P staging slab in loop2
  int bh = blockIdx.x;
  int qt = blockIdx.y;
  int q0 = qt * 32;
  int tid = threadIdx.x;
  int lane = tid & 63, w = tid >> 6;
  int ql = lane & 31, h = lane >> 5;
  int qg = q0 + ql;
  int lo8 = ql * 8;

  const u16* qbase = Qp + (size_t)bh * PKBH + (size_t)qt * 2048;
  const u16* kbase = Kp + (size_t)bh * PKBH;
  const u16* vbase = Vp + (size_t)bh * PKBH;

  short8 qf[4];
#pragma unroll
  for (int c = 0; c < 4; ++c)
    qf[c] = *(const short8*)&qbase[(c * 2 + h) * 256 + lo8];

  // block-diagonal patch band
  int qa = (qg < 2000) ? (qg / 10) : -1;
  int band_lo = 1 << 30, band_hi = -(1 << 30);
  if (q0 < 2000) {
    int hi_row = (q0 + 31 < 1999) ? q0 + 31 : 1999;
    band_lo = (q0 / 10) * 10;
    band_hi = (hi_row / 10) * 10 + 10;
  }
  const float* sfb = &selfS[(size_t)bh * 20000];

  int t0 = w * 16;
  int t1 = t0 + 16; if (t1 > 63) t1 = 63;

  u32 pb[16][8];                 // packed unnormalized e (bf16 pairs)
  short8 kf[4], kfn[4], vf[4];
  f32x16 oacc0 = {}, oacc1 = {};

  // ====== loop 1: loads + QK + exp + pack + PV (no global stores) ========
#pragma unroll
  for (int c = 0; c < 4; ++c)
    kf[c] = *(const short8*)&kbase[(size_t)t0 * 2048 + (c * 2 + h) * 256 + lo8];
  float ssum = 0.f;
#pragma unroll
  for (int i = 0; i < 16; ++i) {
    int t = t0 + i;
    if (t < t1) {
      int tn = (t + 1 < t1) ? t + 1 : t0;
#pragma unroll
      for (int c = 0; c < 4; ++c)
        vf[c] = *(const short8*)&vbase[(size_t)t * 2048 + (c * 2 + h) * 256 + lo8];
#pragma unroll
      for (int c = 0; c < 4; ++c)
        kfn[c] = *(const short8*)&kbase[(size_t)tn * 2048 + (c * 2 + h) * 256 + lo8];
      f32x16 acc = {};
#pragma unroll
      for (int c = 0; c < 4; ++c)
        acc = __builtin_amdgcn_mfma_f32_32x32x16_bf16(kf[c], qf[c], acc, 0, 0, 0);
      int kt = t * 32;
      float e[16];
      if ((kt < band_hi) && (kt + 32 > band_lo)) {
#pragma unroll
        for (int r = 0; r < 16; ++r) {
          int kc = kt + (r & 3) + 8 * (r >> 2) + 4 * h;
          float sc = acc[r];
          if (qa >= 0 && kc < 2000 && (kc / 10) == qa)
            sc = sfb[qa * 100 + (qg - qa * 10) * 10 + (kc - qa * 10)];
          e[r] = __expf(sc);
        }
      } else {
#pragma unroll
        for (int r = 0; r < 16; ++r) e[r] = __expf(acc[r]);
      }
      if (t == 62) {             // mask k-pad [2009,2016)
#pragma unroll
        for (int r = 0; r < 16; ++r) {
          int kc = kt + (r & 3) + 8 * (r >> 2) + 4 * h;
          if (kc >= NTOK) e[r] = 0.f;
        }
      }
#pragma unroll
      for (int r2 = 0; r2 < 8; ++r2) {
        pb[i][r2] = cvtpk(e[2 * r2], e[2 * r2 + 1]);
        ssum += e[2 * r2] + e[2 * r2 + 1];
      }
      // ---- redistribute pb -> PV B-fragments; PV accumulate ----
      u32 p00 = __shfl_xor(pb[i][0], 32), p01 = __shfl_xor(pb[i][1], 32);
      u32 p10 = __shfl_xor(pb[i][2], 32), p11 = __shfl_xor(pb[i][3], 32);
      u32 p20 = __shfl_xor(pb[i][4], 32), p21 = __shfl_xor(pb[i][5], 32);
      u32 p30 = __shfl_xor(pb[i][6], 32), p31 = __shfl_xor(pb[i][7], 32);
      u32 b0[4], b1[4];
      b0[0] = h ? p10 : pb[i][0];  b0[1] = h ? p11 : pb[i][1];
      b0[2] = h ? pb[i][2] : p00;  b0[3] = h ? pb[i][3] : p01;
      b1[0] = h ? p30 : pb[i][4];  b1[1] = h ? p31 : pb[i][5];
      b1[2] = h ? pb[i][6] : p20;  b1[3] = h ? pb[i][7] : p21;
      short8 B0, B1;
      __builtin_memcpy(&B0, b0, 16);
      __builtin_memcpy(&B1, b1, 16);
      oacc0 = __builtin_amdgcn_mfma_f32_32x32x16_bf16(vf[0], B0, oacc0, 0, 0, 0);
      oacc1 = __builtin_amdgcn_mfma_f32_32x32x16_bf16(vf[2], B0, oacc1, 0, 0, 0);
      oacc0 = __builtin_amdgcn_mfma_f32_32x32x16_bf16(vf[1], B1, oacc0, 0, 0, 0);
      oacc1 = __builtin_amdgcn_mfma_f32_32x32x16_bf16(vf[3], B1, oacc1, 0, 0, 0);
#pragma unroll
      for (int c = 0; c < 4; ++c) kf[c] = kfn[c];
    }
  }
  ssum += __shfl_xor(ssum, 32);
  if (lane < 32) s_sum[w][ql] = ssum;
  __syncthreads();
  if (tid < 32)
    s_inv[tid] = 1.0f / (s_sum[0][tid] + s_sum[1][tid] + s_sum[2][tid] + s_sum[3][tid]);
  __syncthreads();

  // ====== loop 2: row-major sequential store stream ======================
  u32* stage = (u32*)&s_o[w][0][0];   // 8 KB wave-private slab: [32 rows][64 u32]
  int kwbase = t0 * 32;
#pragma unroll
  for (int cs = 0; cs < 4; ++cs) {
    // ---- stage 4 tiles of packed pairs, semantic col order, swizzled ----
#pragma unroll
    for (int i2 = 0; i2 < 4; ++i2) {
      int t = t0 + cs * 4 + i2;
      if (t < t1) {
#pragma unroll
        for (int r2 = 0; r2 < 8; ++r2) {
          int c = i2 * 16 + ((r2 & 1) + 4 * (r2 >> 1) + 2 * h);  // pair index
          stage[ql * 64 + (c ^ (ql & 31))] = pb[cs * 4 + i2][r2];
        }
      }
    }
    // ---- write 32 rows x 2 half-runs of 64 consecutive dwords ----
#pragma unroll
    for (int s = 0; s < 64; ++s) {
      int R = s >> 1, hf = s & 1;
      int grow = q0 + R;
      if (grow < NTOK) {
        int col = kwbase + cs * 128 + hf * 64 + lane;
        if (col < NTOK) {
          u32 u = stage[R * 64 + ((hf * 32 + (lane >> 1)) ^ (R & 31))];
          float f = __uint_as_float((lane & 1) ? (u & 0xffff0000u) : (u << 16)) * s_inv[R];
          attn[((size_t)bh * NTOK + grow) * NTOK + col] = f;
        }
      }
    }
  }
  __syncthreads();   // stage slabs dead; s_o reused for O combine

  // ---- combine partial O across waves via LDS (normalize here) ----
#pragma unroll
  for (int r = 0; r < 16; ++r) {
    int d = (r & 3) + 8 * (r >> 2) + 4 * h;
    s_o[w][d][ql] = oacc0[r];
    s_o[w][d + 32][ql] = oacc1[r];
  }
  __syncthreads();
  {
    int q = tid & 31, dg = tid >> 5;          // 8 d's per thread
    int qg2 = q0 + q;
    if (qg2 < NTOK) {
      float invq = s_inv[q];
      int b_ = bh >> 2, hd = bh & 3;
      u16* orow = &Ob[((size_t)(b_ * NTOK + qg2)) * 256 + hd * 64 + dg * 8];
      u32 wpk[4];
#pragma unroll
      for (int j = 0; j < 4; ++j) {
        int d = dg * 8 + 2 * j;
        float a = (s_o[0][d][q] + s_o[1][d][q] + s_o[2][d][q] + s_o[3][d][q]) * invq;
        float b = (s_o[0][d + 1][q] + s_o[1][d + 1][q] + s_o[2][d + 1][q] + s_o[3][d + 1][q]) * invq;
        wpk[j] = pk2(a, b);
      }
      *(uint4*)orow = make_uint4(wpk[0], wpk[1], wpk[2], wpk[3]);
    }
  }
}

// ---------------- output GEMM (m97-style): [8036,256] x [1024,256]^T + bias --
__global__ __launch_bounds__(256) void k_gemm_out(
    const u16* __restrict__ A, const u16* __restrict__ Bt,
    const float* __restrict__ bias, float* __restrict__ C)
{
  __shared__ u16 Asm[128 * 64];
  __shared__ u16 Bsm[128 * 64];
  int mt = blockIdx.x * 128, nt = blockIdx.y * 128;
  int tid = threadIdx.x, lane = tid & 63, w = tid >> 6;
  int wm = w >> 1, wn = w & 1;
  int fr = lane & 15, fq = lane >> 4;
  int srow = w * 32 + (lane >> 3);
  int scol = (lane & 7) * 8;
  f32x4 acc[4][4];
#pragma unroll
  for (int a = 0; a < 4; ++a)
#pragma unroll
    for (int b = 0; b < 4; ++b) acc[a][b] = (f32x4){0.f, 0.f, 0.f, 0.f};

  for (int kt = 0; kt < 256; kt += 64) {
#pragma unroll
    for (int j = 0; j < 4; ++j) {
      int r = srow + j * 8;
      int am = mt + r; if (am >= M8) am = 0;
      gload_lds16(A + (size_t)am * 256 + kt + scol, Asm + (size_t)(w * 32 + j * 8) * 64);
      gload_lds16(Bt + (size_t)(nt + r) * 256 + kt + scol, Bsm + (size_t)(w * 32 + j * 8) * 64);
    }
    __syncthreads();
#pragma unroll
    for (int cs = 0; cs < 2; ++cs) {
      short8 af[4], bf[4];
#pragma unroll
      for (int i = 0; i < 4; ++i) {
        af[i] = *(const short8*)&Asm[(size_t)(wm * 64 + i * 16 + fr) * 64 + cs * 32 + fq * 8];
        bf[i] = *(const short8*)&Bsm[(size_t)(wn * 64 + i * 16 + fr) * 64 + cs * 32 + fq * 8];
      }
#pragma unroll
      for (int mi = 0; mi < 4; ++mi)
#pragma unroll
        for (int ni = 0; ni < 4; ++ni)
          acc[mi][ni] = __builtin_amdgcn_mfma_f32_16x16x32_bf16(af[mi], bf[ni], acc[mi][ni], 0, 0, 0);
    }
    __syncthreads();
  }

#pragma unroll
  for (int ni = 0; ni < 4; ++ni) {
    int n = nt + wn * 64 + ni * 16 + fr;
    float bn = bias[n];
#pragma unroll
    for (int mi = 0; mi < 4; ++mi)
#pragma unroll
      for (int i = 0; i < 4; ++i) {
        int m = mt + wm * 64 + mi * 16 + fq * 4 + i;
        if (m < M8) C[(size_t)m * DMOD + n] = acc[mi][ni][i] + bn;
      }
  }
}

extern "C" void kernel_launch(void* const* d_in, const int* in_sizes, int n_in,
                              void* d_out, int out_size, void* d_ws, size_t ws_size,
                              hipStream_t stream) {
  (void)in_sizes; (void)n_in; (void)out_size; (void)ws_size;
  const float* x    = (const float*)d_in[0];
  const float* Wqkv = (const float*)d_in[1];
  const float* Wqs  = (const float*)d_in[2];
  const float* Wout = (const float*)d_in[3];
  const float* bout = (const float*)d_in[4];
  float* out  = (float*)d_out;
  float* attn = out + (size_t)M8 * DMOD;

  char* ws = (char*)d_ws;
  u16*   xb    = (u16*)(ws);                      // 16,457,728
  u16*   WtCat = (u16*)(ws + 16457728);           //  2,621,440
  u16*   WtOut = (u16*)(ws + 19079168);           //    524,288
  u16*   Qp    = (u16*)(ws + 19603456);           //  4,128,768
  u16*   Kp    = (u16*)(ws + 23732224);           //  4,128,768
  u16*   Vp    = (u16*)(ws + 27860992);           //  4,128,768
  u16*   Qsb   = (u16*)(ws + 31989760);           //  4,114,432
  u16*   Ksb   = (u16*)(ws + 36104192);           //  4,114,432
  u16*   Ob    = (u16*)(ws + 40218624);           //  4,114,432
  float* selfS = (float*)(ws + 44333056);         //  1,280,000 (end ~45.6 MB)

  k_conv_x<<<dim3(8036), dim3(256), 0, stream>>>(x, xb);
  k_conv_wcat<<<dim3(5120), dim3(256), 0, stream>>>(Wqkv, Wqs, WtCat);
  k_conv_wout<<<dim3(1024), dim3(256), 0, stream>>>(Wout, WtOut);
  k_gemm_proj<<<dim3(63, 10), dim3(256), 0, stream>>>(xb, WtCat, Qp, Kp, Vp, Qsb, Ksb);
  k_self<<<dim3(3200), dim3(128), 0, stream>>>(Qsb, Ksb, selfS);
  k_attn10<<<dim3(16, 63), dim3(256), 0, stream>>>(Qp, Kp, Vp, selfS, attn, Ob);
  k_gemm_out<<<dim3(63, 8), dim3(256), 0, stream>>>(Ob, WtOut, bout, out);
}